// Round 1
// baseline (91.745 us; speedup 1.0000x reference)
//
#include <hip/hip_runtime.h>
#include <cstdint>

typedef short bf16x8 __attribute__((ext_vector_type(8)));
typedef float f32x4 __attribute__((ext_vector_type(4)));
typedef unsigned short u16;
typedef unsigned int u32;

#define DEVI static __device__ __forceinline__

// ---------- helpers ----------

DEVI u16 f2bf(float f) {              // fp32 -> bf16 RTNE (inputs are finite)
  u32 x = __builtin_bit_cast(u32, f);
  x += 0x7fffu + ((x >> 16) & 1u);
  return (u16)(x >> 16);
}

DEVI u32 pack_bf2(float lo, float hi) {
  return (u32)f2bf(lo) | ((u32)f2bf(hi) << 16);
}

DEVI u32 cvt_pk_bf16(float lo, float hi) {
  u32 r;
  asm("v_cvt_pk_bf16_f32 %0, %1, %2" : "=v"(r) : "v"(lo), "v"(hi));
  return r;
}

DEVI f32x4 mfma16(bf16x8 a, bf16x8 b, f32x4 c) {
  return __builtin_amdgcn_mfma_f32_16x16x32_bf16(a, b, c, 0, 0, 0);
}

DEVI void load_lds16(const void* g, void* l) {   // 16B per lane, dest = base + lane*16
  __builtin_amdgcn_global_load_lds(
      (const __attribute__((address_space(1))) u32*)g,
      (__attribute__((address_space(3))) u32*)l, 16, 0, 0);
}

// CSCALE = log2(e) / sqrt(DK=32): folded into Q so attention uses raw exp2
#define CSCALE 0.2550351f

// ---------- kernel 1: fp32 -> bf16 conversion ----------
// dst layout: [xa 1048576][xb 1048576][w0..w5 each 65536]
__global__ __launch_bounds__(256) void convert_kernel(
    const float* __restrict__ xa, const float* __restrict__ xb,
    const float* __restrict__ w0, const float* __restrict__ w1,
    const float* __restrict__ w2, const float* __restrict__ w3,
    const float* __restrict__ w4, const float* __restrict__ w5,
    u16* __restrict__ dst) {
  int i = (int)(blockIdx.x * 256u + threadIdx.x) * 8;
  const float* s;
  if (i < 1048576) {
    s = xa + i;
  } else if (i < 2097152) {
    s = xb + (i - 1048576);
  } else {
    int t = i - 2097152;
    int j = t >> 16, o = t & 65535;
    s = (j == 0 ? w0 : j == 1 ? w1 : j == 2 ? w2 : j == 3 ? w3 : j == 4 ? w4 : w5) + o;
  }
  float4 a = *(const float4*)s;
  float4 b = *(const float4*)(s + 4);
  uint4 o4;
  o4.x = pack_bf2(a.x, a.y);
  o4.y = pack_bf2(a.z, a.w);
  o4.z = pack_bf2(b.x, b.y);
  o4.w = pack_bf2(b.z, b.w);
  *(uint4*)(dst + i) = o4;
}

// ---------- kernel 2: fused projections (5 jobs) ----------
// jobs: 0 = Q(x_a, wq)*CSCALE -> [BH,2048,32]
//       1 = K(x_a, wk_a) -> [BH,4096,32] rows 0..2047
//       2 = Vt(x_a, wv_a) -> [BH,32,4096] cols 0..2047 (permuted in 64-blocks)
//       3 = K(x_b, wk_b) rows 2048..4095
//       4 = Vt(x_b, wv_b) cols 2048..4095
__global__ __launch_bounds__(256) void proj_kernel(
    const u16* __restrict__ xa_bf, const u16* __restrict__ xb_bf,
    const u16* __restrict__ wbase,
    const float* __restrict__ b0, const float* __restrict__ b1,
    const float* __restrict__ b2, const float* __restrict__ b3,
    const float* __restrict__ b4,
    u16* __restrict__ Qo, u16* __restrict__ Ko, u16* __restrict__ Vto) {
  int job = blockIdx.z;
  const u16* A = (job <= 2) ? xa_bf : xb_bf;
  const u16* W = wbase + job * 65536;
  const float* bias = job == 0 ? b0 : job == 1 ? b1 : job == 2 ? b2 : job == 3 ? b3 : b4;
  int mode = (job == 0) ? 0 : (job == 1 || job == 3) ? 1 : 2;
  int soff = (job >= 3) ? 2048 : 0;

  int tid = threadIdx.x, wid = tid >> 6, lane = tid & 63, g = lane >> 4, c = lane & 15;
  int m0 = blockIdx.x * 64, n0 = blockIdx.y * 64;
  const u16* Ap = A + (m0 + wid * 16 + c) * 256 + g * 8;
  const u16* Wp = W + (n0 + c) * 256 + g * 8;
  f32x4 acc[4] = {};
#pragma unroll
  for (int kk = 0; kk < 256; kk += 32) {
    bf16x8 af = *(const bf16x8*)(Ap + kk);
#pragma unroll
    for (int nt = 0; nt < 4; ++nt) {
      bf16x8 bfr = *(const bf16x8*)(Wp + nt * 4096 + kk);
      acc[nt] = mfma16(af, bfr, acc[nt]);
    }
  }
#pragma unroll
  for (int nt = 0; nt < 4; ++nt) {
    int f = n0 + nt * 16 + c;
    float bv = bias[f];
    int h = f >> 5, d = f & 31;
#pragma unroll
    for (int r = 0; r < 4; ++r) {
      int m = m0 + wid * 16 + g * 4 + r;
      int bq = m >> 11, n = m & 2047;
      int bh = bq * 8 + h;
      float y = acc[nt][r] + bv;
      if (mode == 0) {
        Qo[(bh * 2048 + n) * 32 + d] = f2bf(y * CSCALE);
      } else if (mode == 1) {
        Ko[(bh * 4096 + soff + n) * 32 + d] = f2bf(y);
      } else {
        int nk = soff + n;
        int col = (nk & ~63) | ((nk & 15) << 2) | ((nk >> 4) & 3);
        Vto[(bh * 32 + d) * 4096 + col] = f2bf(y);
      }
    }
  }
}

// ---------- kernel 3: flash attention (no-max softmax) ----------
// grid 512: xcd-affine bh mapping; block = 4 waves x 16 q-rows = 64 q-rows
__global__ __launch_bounds__(256) void attn_kernel(
    const u16* __restrict__ Q, const u16* __restrict__ K,
    const u16* __restrict__ Vt, u16* __restrict__ Z) {
  __shared__ __align__(16) unsigned char sbuf[25600];
  // [0,8192): K double buffer (2 x 64keys x 64B, xor-swizzled)
  // [8192,16384): Vt double buffer (2 x 32d x 128B, xor-swizzled)
  // [16384,25600): P scratch, per wave 16 rows x 144B
  int bid = blockIdx.x;
  int xcd = bid & 7, slot = bid >> 3;
  int bh = (xcd << 1) | (slot & 1);
  int qi = slot >> 1;
  int tid = threadIdx.x, wid = tid >> 6, lane = tid & 63;
  int g = lane >> 4, c = lane & 15;
  int qbase = qi * 64 + wid * 16;

  const u16* Kbh = K + bh * (4096 * 32);
  const u16* Vtbh = Vt + bh * (32 * 4096);

  bf16x8 qf = *(const bf16x8*)(Q + (bh * 2048 + qbase + c) * 32 + g * 8);

  // lane-constant swizzled LDS read addresses
  int kaddr = c * 64 + ((g ^ ((c >> 1) & 3)) << 4);
  int vaddr = c * 128 + ((g ^ (c & 3)) << 4) + (((c >> 2) & 1) << 6);
  unsigned char* pbuf = sbuf + 16384 + wid * 2304;
  int pwr = (g * 4) * 144 + c * 8;  // + r*144
  int prd = c * 144 + g * 16;

  // staging source offsets (linear LDS dest, inverse-swizzled global src)
  int o = wid * 1024 + (lane << 4);
  int ko_src = o ^ (((o >> 7) & 3) << 4);
  int vd = o >> 7, vch = (o >> 4) & 7;
  int vo_src = vd * 8192 + ((vch ^ (vd & 7)) << 4);

  f32x4 z0 = {}, z1 = {};
  float lsum[4] = {0.f, 0.f, 0.f, 0.f};

  load_lds16((const unsigned char*)Kbh + ko_src, sbuf + wid * 1024);
  load_lds16((const unsigned char*)Vtbh + vo_src, sbuf + 8192 + wid * 1024);
  __syncthreads();

  for (int it = 0; it < 64; ++it) {
    int cur = it & 1;
    if (it + 1 < 64) {  // prefetch next tile into other buffer
      int kb = (it + 1) * 64;
      load_lds16((const unsigned char*)Kbh + kb * 64 + ko_src,
                 sbuf + (cur ^ 1) * 4096 + wid * 1024);
      load_lds16((const unsigned char*)Vtbh + kb * 2 + vo_src,
                 sbuf + 8192 + (cur ^ 1) * 4096 + wid * 1024);
    }
    const unsigned char* kbuf = sbuf + cur * 4096;
    const unsigned char* vbuf = sbuf + 8192 + cur * 4096;

    bf16x8 kf0 = *(const bf16x8*)(kbuf + kaddr);
    bf16x8 kf1 = *(const bf16x8*)(kbuf + kaddr + 1024);
    bf16x8 kf2 = *(const bf16x8*)(kbuf + kaddr + 2048);
    bf16x8 kf3 = *(const bf16x8*)(kbuf + kaddr + 3072);
    f32x4 zz = {};
    f32x4 s0 = mfma16(qf, kf0, zz);
    f32x4 s1 = mfma16(qf, kf1, zz);
    f32x4 s2 = mfma16(qf, kf2, zz);
    f32x4 s3 = mfma16(qf, kf3, zz);

    float p0[4], p1[4], p2[4], p3[4];
#pragma unroll
    for (int r = 0; r < 4; ++r) {
      p0[r] = __builtin_amdgcn_exp2f(s0[r]);
      p1[r] = __builtin_amdgcn_exp2f(s1[r]);
      p2[r] = __builtin_amdgcn_exp2f(s2[r]);
      p3[r] = __builtin_amdgcn_exp2f(s3[r]);
      lsum[r] += (p0[r] + p1[r]) + (p2[r] + p3[r]);
      *(u32*)(pbuf + pwr + r * 144) = cvt_pk_bf16(p0[r], p1[r]);
      *(u32*)(pbuf + pwr + r * 144 + 4) = cvt_pk_bf16(p2[r], p3[r]);
    }
    // same-wave LDS transpose roundtrip (DS pipe is in-order per wave)
    bf16x8 pf0 = *(const bf16x8*)(pbuf + prd);
    bf16x8 pf1 = *(const bf16x8*)(pbuf + prd + 64);
    bf16x8 vf00 = *(const bf16x8*)(vbuf + vaddr);
    bf16x8 vf01 = *(const bf16x8*)(vbuf + (vaddr ^ 64));
    bf16x8 vf10 = *(const bf16x8*)(vbuf + vaddr + 2048);
    bf16x8 vf11 = *(const bf16x8*)(vbuf + (vaddr ^ 64) + 2048);
    z0 = mfma16(pf0, vf00, z0);
    z0 = mfma16(pf1, vf01, z0);
    z1 = mfma16(pf0, vf10, z1);
    z1 = mfma16(pf1, vf11, z1);
    __syncthreads();
  }

#pragma unroll
  for (int r = 0; r < 4; ++r) {
    float t = lsum[r];
    t += __shfl_xor(t, 1);
    t += __shfl_xor(t, 2);
    t += __shfl_xor(t, 4);
    t += __shfl_xor(t, 8);
    float inv = 1.0f / t;
    int m = qbase + g * 4 + r;
    int rowbase = ((bh >> 3) * 2048 + m) * 256 + (bh & 7) * 32;
    Z[rowbase + c] = f2bf(z0[r] * inv);
    Z[rowbase + 16 + c] = f2bf(z1[r] * inv);
  }
}

// ---------- kernel 4: out = Z @ w^T + b + x_a (fp32) ----------
__global__ __launch_bounds__(256) void out_kernel(
    const u16* __restrict__ A, const u16* __restrict__ W,
    const float* __restrict__ bias, const float* __restrict__ resid,
    float* __restrict__ out) {
  int tid = threadIdx.x, wid = tid >> 6, lane = tid & 63, g = lane >> 4, c = lane & 15;
  int m0 = blockIdx.x * 64, n0 = blockIdx.y * 64;
  const u16* Ap = A + (m0 + wid * 16 + c) * 256 + g * 8;
  const u16* Wp = W + (n0 + c) * 256 + g * 8;
  f32x4 acc[4] = {};
#pragma unroll
  for (int kk = 0; kk < 256; kk += 32) {
    bf16x8 af = *(const bf16x8*)(Ap + kk);
#pragma unroll
    for (int nt = 0; nt < 4; ++nt) {
      bf16x8 bfr = *(const bf16x8*)(Wp + nt * 4096 + kk);
      acc[nt] = mfma16(af, bfr, acc[nt]);
    }
  }
#pragma unroll
  for (int nt = 0; nt < 4; ++nt) {
    int f = n0 + nt * 16 + c;
    float bv = bias[f];
#pragma unroll
    for (int r = 0; r < 4; ++r) {
      int m = m0 + wid * 16 + g * 4 + r;
      out[m * 256 + f] = acc[nt][r] + bv + resid[m * 256 + f];
    }
  }
}

// ---------- launch ----------
extern "C" void kernel_launch(void* const* d_in, const int* in_sizes, int n_in,
                              void* d_out, int out_size, void* d_ws, size_t ws_size,
                              hipStream_t stream) {
  const float* xa = (const float*)d_in[0];
  const float* xb = (const float*)d_in[1];
  const float* wq_w = (const float*)d_in[2];
  const float* wq_b = (const float*)d_in[3];
  const float* wka_w = (const float*)d_in[4];
  const float* wka_b = (const float*)d_in[5];
  const float* wkb_w = (const float*)d_in[6];
  const float* wkb_b = (const float*)d_in[7];
  const float* wva_w = (const float*)d_in[8];
  const float* wva_b = (const float*)d_in[9];
  const float* wvb_w = (const float*)d_in[10];
  const float* wvb_b = (const float*)d_in[11];
  const float* w_w = (const float*)d_in[12];
  const float* w_b = (const float*)d_in[13];

  u16* ws = (u16*)d_ws;
  u16* xa_bf = ws;                  // 1048576
  u16* xb_bf = ws + 1048576;        // 1048576
  u16* wbf = ws + 2097152;          // 6 * 65536
  u16* Qb = ws + 2490368;           // 1048576
  u16* Kb = ws + 3538944;           // 2097152
  u16* Vtb = ws + 5636096;          // 2097152
  u16* Zb = ws + 7733248;           // 1048576  (total ~17.6 MB)

  convert_kernel<<<1216, 256, 0, stream>>>(xa, xb, wq_w, wka_w, wva_w, wkb_w,
                                           wvb_w, w_w, ws);
  proj_kernel<<<dim3(64, 4, 5), 256, 0, stream>>>(
      xa_bf, xb_bf, wbf, wq_b, wka_b, wva_b, wkb_b, wvb_b, Qb, Kb, Vtb);
  attn_kernel<<<512, 256, 0, stream>>>(Qb, Kb, Vtb, Zb);
  out_kernel<<<dim3(64, 4), 256, 0, stream>>>(Zb, wbf + 5 * 65536, w_b, xa,
                                              (float*)d_out);
}

// Round 2
// 86.758 us; speedup vs baseline: 1.0575x; 1.0575x over previous
//
#include <hip/hip_runtime.h>
#include <cstdint>

typedef short bf16x8 __attribute__((ext_vector_type(8)));
typedef float f32x4 __attribute__((ext_vector_type(4)));
typedef unsigned short u16;
typedef unsigned int u32;

#define DEVI static __device__ __forceinline__

// ---------- helpers ----------

DEVI u16 f2bf(float f) {              // fp32 -> bf16 RTNE (inputs are finite)
  u32 x = __builtin_bit_cast(u32, f);
  x += 0x7fffu + ((x >> 16) & 1u);
  return (u16)(x >> 16);
}

DEVI u32 pack_bf2(float lo, float hi) {
  return (u32)f2bf(lo) | ((u32)f2bf(hi) << 16);
}

DEVI u32 cvt_pk_bf16(float lo, float hi) {
  u32 r;
  asm("v_cvt_pk_bf16_f32 %0, %1, %2" : "=v"(r) : "v"(lo), "v"(hi));
  return r;
}

DEVI f32x4 mfma16(bf16x8 a, bf16x8 b, f32x4 c) {
  return __builtin_amdgcn_mfma_f32_16x16x32_bf16(a, b, c, 0, 0, 0);
}

DEVI void load_lds16(const void* g, void* l) {   // 16B per lane, dest = base + lane*16
  __builtin_amdgcn_global_load_lds(
      (const __attribute__((address_space(1))) u32*)g,
      (__attribute__((address_space(3))) u32*)l, 16, 0, 0);
}

// CSCALE = log2(e) / sqrt(DK=32): folded into Q so attention uses raw exp2
#define CSCALE 0.2550351f

// ---------- kernel 1: fp32 -> bf16 conversion ----------
__global__ __launch_bounds__(256) void convert_kernel(
    const float* __restrict__ xa, const float* __restrict__ xb,
    const float* __restrict__ w0, const float* __restrict__ w1,
    const float* __restrict__ w2, const float* __restrict__ w3,
    const float* __restrict__ w4, const float* __restrict__ w5,
    u16* __restrict__ dst) {
  int i = (int)(blockIdx.x * 256u + threadIdx.x) * 8;
  const float* s;
  if (i < 1048576) {
    s = xa + i;
  } else if (i < 2097152) {
    s = xb + (i - 1048576);
  } else {
    int t = i - 2097152;
    int j = t >> 16, o = t & 65535;
    s = (j == 0 ? w0 : j == 1 ? w1 : j == 2 ? w2 : j == 3 ? w3 : j == 4 ? w4 : w5) + o;
  }
  float4 a = *(const float4*)s;
  float4 b = *(const float4*)(s + 4);
  uint4 o4;
  o4.x = pack_bf2(a.x, a.y);
  o4.y = pack_bf2(a.z, a.w);
  o4.z = pack_bf2(b.x, b.y);
  o4.w = pack_bf2(b.z, b.w);
  *(uint4*)(dst + i) = o4;
}

// ---------- kernel 2: fused projections (5 jobs) ----------
__global__ __launch_bounds__(256) void proj_kernel(
    const u16* __restrict__ xa_bf, const u16* __restrict__ xb_bf,
    const u16* __restrict__ wbase,
    const float* __restrict__ b0, const float* __restrict__ b1,
    const float* __restrict__ b2, const float* __restrict__ b3,
    const float* __restrict__ b4,
    u16* __restrict__ Qo, u16* __restrict__ Ko, u16* __restrict__ Vto) {
  int job = blockIdx.z;
  const u16* A = (job <= 2) ? xa_bf : xb_bf;
  const u16* W = wbase + job * 65536;
  const float* bias = job == 0 ? b0 : job == 1 ? b1 : job == 2 ? b2 : job == 3 ? b3 : b4;
  int mode = (job == 0) ? 0 : (job == 1 || job == 3) ? 1 : 2;
  int soff = (job >= 3) ? 2048 : 0;

  int tid = threadIdx.x, wid = tid >> 6, lane = tid & 63, g = lane >> 4, c = lane & 15;
  int m0 = blockIdx.x * 64, n0 = blockIdx.y * 64;
  const u16* Ap = A + (m0 + wid * 16 + c) * 256 + g * 8;
  const u16* Wp = W + (n0 + c) * 256 + g * 8;
  f32x4 acc[4] = {};
#pragma unroll
  for (int kk = 0; kk < 256; kk += 32) {
    bf16x8 af = *(const bf16x8*)(Ap + kk);
#pragma unroll
    for (int nt = 0; nt < 4; ++nt) {
      bf16x8 bfr = *(const bf16x8*)(Wp + nt * 4096 + kk);
      acc[nt] = mfma16(af, bfr, acc[nt]);
    }
  }
#pragma unroll
  for (int nt = 0; nt < 4; ++nt) {
    int f = n0 + nt * 16 + c;
    float bv = bias[f];
    int h = f >> 5, d = f & 31;
#pragma unroll
    for (int r = 0; r < 4; ++r) {
      int m = m0 + wid * 16 + g * 4 + r;
      int bq = m >> 11, n = m & 2047;
      int bh = bq * 8 + h;
      float y = acc[nt][r] + bv;
      if (mode == 0) {
        Qo[(bh * 2048 + n) * 32 + d] = f2bf(y * CSCALE);
      } else if (mode == 1) {
        Ko[(bh * 4096 + soff + n) * 32 + d] = f2bf(y);
      } else {
        int nk = soff + n;
        int col = (nk & ~63) | ((nk & 15) << 2) | ((nk >> 4) & 3);
        Vto[(bh * 32 + d) * 4096 + col] = f2bf(y);
      }
    }
  }
}

// ---------- kernel 3: flash attention, split-K (2 halves) ----------
// grid 1024: bid -> xcd=bid&7, slot=bid>>3; bh=(xcd<<1)|(slot&1);
// rem=slot>>1: ks=rem&1 (key half), qi=rem>>1 (32 q-tiles of 64 rows)
// Triple-buffered K/V staging, one raw s_barrier per 64-key iteration,
// counted vmcnt prefetch (depth 1), fp32 unnormalized output + row sums.
__global__ __launch_bounds__(256) void attn_kernel(
    const u16* __restrict__ Q, const u16* __restrict__ K,
    const u16* __restrict__ Vt, float* __restrict__ Zp, float* __restrict__ S) {
  __shared__ __align__(16) unsigned char sbuf[33792];
  // [0,12288): K triple buffer (3 x 64keys x 64B, xor-swizzled)
  // [12288,24576): Vt triple buffer (3 x 32d x 128B, xor-swizzled)
  // [24576,33792): P scratch, per wave 16 rows x 144B
  int bid = blockIdx.x;
  int xcd = bid & 7, slot = bid >> 3;
  int bh = (xcd << 1) | (slot & 1);
  int rem = slot >> 1;
  int ks = rem & 1, qi = rem >> 1;
  int tid = threadIdx.x, wid = tid >> 6, lane = tid & 63;
  int g = lane >> 4, c = lane & 15;
  int qbase = qi * 64 + wid * 16;

  const unsigned char* Kb =
      (const unsigned char*)K + ((size_t)bh * 4096 + ks * 2048) * 64;
  const unsigned char* Vb =
      (const unsigned char*)Vt + ((size_t)bh * 32 * 4096 + ks * 2048) * 2;

  bf16x8 qf = *(const bf16x8*)(Q + ((size_t)bh * 2048 + qbase + c) * 32 + g * 8);

  // lane-constant swizzled LDS read addresses
  int kaddr = c * 64 + ((g ^ ((c >> 1) & 3)) << 4);
  int vaddr = c * 128 + ((g ^ (c & 3)) << 4) + (((c >> 2) & 1) << 6);
  unsigned char* pbuf = sbuf + 24576 + wid * 2304;
  int pwr = g * 576 + c * 8;  // + r*144
  int prd = c * 144 + g * 16;

  // staging source offsets (linear LDS dest, inverse-swizzled global src)
  int o = wid * 1024 + (lane << 4);
  int ko_src = o ^ (((o >> 7) & 3) << 4);
  int vd = o >> 7, vch = (o >> 4) & 7;
  int vo_src = vd * 8192 + ((vch ^ (vd & 7)) << 4);

  f32x4 z0 = {}, z1 = {};
  float lsum[4] = {0.f, 0.f, 0.f, 0.f};

  // prologue: stage tile 0 into buffer 0
  load_lds16(Kb + ko_src, sbuf + wid * 1024);
  load_lds16(Vb + vo_src, sbuf + 12288 + wid * 1024);

  int cur = 0;
  for (int t = 0; t < 32; ++t) {
    int nxt = cur + 1;
    if (nxt == 3) nxt = 0;
    if (t + 1 < 32) {  // prefetch tile t+1 into buffer nxt
      load_lds16(Kb + (t + 1) * 4096 + ko_src, sbuf + nxt * 4096 + wid * 1024);
      load_lds16(Vb + (t + 1) * 128 + vo_src,
                 sbuf + 12288 + nxt * 4096 + wid * 1024);
      __builtin_amdgcn_sched_barrier(0);
      asm volatile("s_waitcnt vmcnt(2)" ::: "memory");  // tile t (mine) done
    } else {
      __builtin_amdgcn_sched_barrier(0);
      asm volatile("s_waitcnt vmcnt(0)" ::: "memory");
    }
    __builtin_amdgcn_s_barrier();   // all waves' tile-t loads done
    __builtin_amdgcn_sched_barrier(0);

    const unsigned char* kbuf = sbuf + cur * 4096;
    const unsigned char* vbuf = sbuf + 12288 + cur * 4096;

    bf16x8 kf0 = *(const bf16x8*)(kbuf + kaddr);
    bf16x8 kf1 = *(const bf16x8*)(kbuf + kaddr + 1024);
    bf16x8 kf2 = *(const bf16x8*)(kbuf + kaddr + 2048);
    bf16x8 kf3 = *(const bf16x8*)(kbuf + kaddr + 3072);
    f32x4 zz = {};
    __builtin_amdgcn_s_setprio(1);
    f32x4 s0 = mfma16(qf, kf0, zz);
    f32x4 s1 = mfma16(qf, kf1, zz);
    f32x4 s2 = mfma16(qf, kf2, zz);
    f32x4 s3 = mfma16(qf, kf3, zz);
    __builtin_amdgcn_s_setprio(0);

    float p0[4], p1[4], p2[4], p3[4];
#pragma unroll
    for (int r = 0; r < 4; ++r) {
      p0[r] = __builtin_amdgcn_exp2f(s0[r]);
      p1[r] = __builtin_amdgcn_exp2f(s1[r]);
      p2[r] = __builtin_amdgcn_exp2f(s2[r]);
      p3[r] = __builtin_amdgcn_exp2f(s3[r]);
      lsum[r] += (p0[r] + p1[r]) + (p2[r] + p3[r]);
      uint2 pw;
      pw.x = cvt_pk_bf16(p0[r], p1[r]);
      pw.y = cvt_pk_bf16(p2[r], p3[r]);
      *(uint2*)(pbuf + pwr + r * 144) = pw;   // single b64 write
    }
    // same-wave LDS transpose roundtrip
    bf16x8 pf0 = *(const bf16x8*)(pbuf + prd);
    bf16x8 pf1 = *(const bf16x8*)(pbuf + prd + 64);
    bf16x8 vf00 = *(const bf16x8*)(vbuf + vaddr);
    bf16x8 vf01 = *(const bf16x8*)(vbuf + (vaddr ^ 64));
    bf16x8 vf10 = *(const bf16x8*)(vbuf + vaddr + 2048);
    bf16x8 vf11 = *(const bf16x8*)(vbuf + (vaddr ^ 64) + 2048);
    __builtin_amdgcn_s_setprio(1);
    z0 = mfma16(pf0, vf00, z0);
    z0 = mfma16(pf1, vf01, z0);
    z1 = mfma16(pf0, vf10, z1);
    z1 = mfma16(pf1, vf11, z1);
    __builtin_amdgcn_s_setprio(0);
    cur = nxt;
  }

  size_t zrow = ((size_t)ks * 16 + bh) * 2048;
#pragma unroll
  for (int r = 0; r < 4; ++r) {
    float tsum = lsum[r];
    tsum += __shfl_xor(tsum, 1);
    tsum += __shfl_xor(tsum, 2);
    tsum += __shfl_xor(tsum, 4);
    tsum += __shfl_xor(tsum, 8);
    int m = qbase + g * 4 + r;
    float* zp = Zp + (zrow + m) * 32;
    zp[c] = z0[r];
    zp[16 + c] = z1[r];
    if (c == 0) S[zrow + m] = tsum;
  }
}

// ---------- kernel 4: combine + out = Z @ w^T + b + x_a (fp32) ----------
// 8 waves/block: wid&3 -> m quarter, wid>>2 -> n half
__global__ __launch_bounds__(512) void out_kernel(
    const float* __restrict__ Zp, const float* __restrict__ S,
    const u16* __restrict__ W, const float* __restrict__ bias,
    const float* __restrict__ resid, float* __restrict__ out) {
  int tid = threadIdx.x, wid = tid >> 6, lane = tid & 63, g = lane >> 4, c = lane & 15;
  int m0 = blockIdx.x * 64, n0 = blockIdx.y * 64;
  int mw = m0 + (wid & 3) * 16;
  int nb = n0 + (wid >> 2) * 32;
  int mrow = mw + c;
  int bq = mrow >> 11, n = mrow & 2047;
  const u16* Wp = W + (nb + c) * 256 + g * 8;
  f32x4 acc[2] = {};
#pragma unroll
  for (int h = 0; h < 8; ++h) {
    int bh = bq * 8 + h;
    const float* za = Zp + ((size_t)bh * 2048 + n) * 32 + g * 8;
    const float* zb = za + (size_t)16 * 2048 * 32;
    float4 a0 = *(const float4*)za;
    float4 a1 = *(const float4*)(za + 4);
    float4 b0 = *(const float4*)zb;
    float4 b1 = *(const float4*)(zb + 4);
    float inv = 1.0f / (S[(size_t)bh * 2048 + n] + S[(size_t)(16 + bh) * 2048 + n]);
    union { u32 u[4]; bf16x8 v; } cv;
    cv.u[0] = pack_bf2((a0.x + b0.x) * inv, (a0.y + b0.y) * inv);
    cv.u[1] = pack_bf2((a0.z + b0.z) * inv, (a0.w + b0.w) * inv);
    cv.u[2] = pack_bf2((a1.x + b1.x) * inv, (a1.y + b1.y) * inv);
    cv.u[3] = pack_bf2((a1.z + b1.z) * inv, (a1.w + b1.w) * inv);
    bf16x8 af = cv.v;
#pragma unroll
    for (int nt = 0; nt < 2; ++nt) {
      bf16x8 bfr = *(const bf16x8*)(Wp + nt * 4096 + h * 32);
      acc[nt] = mfma16(af, bfr, acc[nt]);
    }
  }
#pragma unroll
  for (int nt = 0; nt < 2; ++nt) {
    int f = nb + nt * 16 + c;
    float bv = bias[f];
#pragma unroll
    for (int r = 0; r < 4; ++r) {
      int m = mw + g * 4 + r;
      out[(size_t)m * 256 + f] = acc[nt][r] + bv + resid[(size_t)m * 256 + f];
    }
  }
}

// ---------- launch ----------
extern "C" void kernel_launch(void* const* d_in, const int* in_sizes, int n_in,
                              void* d_out, int out_size, void* d_ws, size_t ws_size,
                              hipStream_t stream) {
  const float* xa = (const float*)d_in[0];
  const float* xb = (const float*)d_in[1];
  const float* wq_w = (const float*)d_in[2];
  const float* wq_b = (const float*)d_in[3];
  const float* wka_w = (const float*)d_in[4];
  const float* wka_b = (const float*)d_in[5];
  const float* wkb_w = (const float*)d_in[6];
  const float* wkb_b = (const float*)d_in[7];
  const float* wva_w = (const float*)d_in[8];
  const float* wva_b = (const float*)d_in[9];
  const float* wvb_w = (const float*)d_in[10];
  const float* wvb_b = (const float*)d_in[11];
  const float* w_w = (const float*)d_in[12];
  const float* w_b = (const float*)d_in[13];

  u16* ws = (u16*)d_ws;
  u16* xa_bf = ws;                  // 1048576
  u16* xb_bf = ws + 1048576;        // 1048576
  u16* wbf = ws + 2097152;          // 6 * 65536
  u16* Qb = ws + 2490368;           // 1048576
  u16* Kb = ws + 3538944;           // 2097152
  u16* Vtb = ws + 5636096;          // 2097152
  float* Zp = (float*)(ws + 7733248);          // 2*16*2048*32 fp32 = 8 MB
  float* S = (float*)((char*)d_ws + 23855104); // 2*16*2048 fp32 = 256 KB
  // total ws: ~24.1 MB

  convert_kernel<<<1216, 256, 0, stream>>>(xa, xb, wq_w, wka_w, wva_w, wkb_w,
                                           wvb_w, w_w, ws);
  proj_kernel<<<dim3(64, 4, 5), 256, 0, stream>>>(
      xa_bf, xb_bf, wbf, wq_b, wka_b, wva_b, wkb_b, wvb_b, Qb, Kb, Vtb);
  attn_kernel<<<1024, 256, 0, stream>>>(Qb, Kb, Vtb, Zp, S);
  out_kernel<<<dim3(64, 4), 512, 0, stream>>>(Zp, S, wbf + 5 * 65536, w_b, xa,
                                              (float*)d_out);
}

// Round 3
// 78.352 us; speedup vs baseline: 1.1709x; 1.1073x over previous
//
#include <hip/hip_runtime.h>
#include <cstdint>

typedef short bf16x8 __attribute__((ext_vector_type(8)));
typedef float f32x4 __attribute__((ext_vector_type(4)));
typedef unsigned short u16;
typedef unsigned int u32;

#define DEVI static __device__ __forceinline__

// ---------- helpers ----------

DEVI u16 f2bf(float f) {              // fp32 -> bf16 RTNE (inputs are finite)
  u32 x = __builtin_bit_cast(u32, f);
  x += 0x7fffu + ((x >> 16) & 1u);
  return (u16)(x >> 16);
}

DEVI u32 pack_bf2(float lo, float hi) {
  return (u32)f2bf(lo) | ((u32)f2bf(hi) << 16);
}

DEVI u32 cvt_pk_bf16(float lo, float hi) {
  u32 r;
  asm("v_cvt_pk_bf16_f32 %0, %1, %2" : "=v"(r) : "v"(lo), "v"(hi));
  return r;
}

DEVI f32x4 mfma16(bf16x8 a, bf16x8 b, f32x4 c) {
  return __builtin_amdgcn_mfma_f32_16x16x32_bf16(a, b, c, 0, 0, 0);
}

DEVI void load_lds16(const void* g, void* l) {   // 16B per lane, dest = base + lane*16
  __builtin_amdgcn_global_load_lds(
      (const __attribute__((address_space(1))) u32*)g,
      (__attribute__((address_space(3))) u32*)l, 16, 0, 0);
}

// CSCALE = log2(e) / sqrt(DK=32): folded into Q so attention uses raw exp2
#define CSCALE 0.2550351f

// key-row permutation within each 64-key tile (see attn swapped-QK derivation)
DEVI int rho(int k) {
  return ((k >> 5) << 5) | (((k >> 2) & 1) << 4) | (((k >> 3) & 3) << 2) | (k & 3);
}

// ---------- kernel 1: fp32 -> bf16 conversion ----------
__global__ __launch_bounds__(256) void convert_kernel(
    const float* __restrict__ xa, const float* __restrict__ xb,
    const float* __restrict__ w0, const float* __restrict__ w1,
    const float* __restrict__ w2, const float* __restrict__ w3,
    const float* __restrict__ w4, const float* __restrict__ w5,
    u16* __restrict__ dst) {
  int i = (int)(blockIdx.x * 256u + threadIdx.x) * 8;
  const float* s;
  if (i < 1048576) {
    s = xa + i;
  } else if (i < 2097152) {
    s = xb + (i - 1048576);
  } else {
    int t = i - 2097152;
    int j = t >> 16, o = t & 65535;
    s = (j == 0 ? w0 : j == 1 ? w1 : j == 2 ? w2 : j == 3 ? w3 : j == 4 ? w4 : w5) + o;
  }
  float4 a = *(const float4*)s;
  float4 b = *(const float4*)(s + 4);
  uint4 o4;
  o4.x = pack_bf2(a.x, a.y);
  o4.y = pack_bf2(a.z, a.w);
  o4.z = pack_bf2(b.x, b.y);
  o4.w = pack_bf2(b.z, b.w);
  *(uint4*)(dst + i) = o4;
}

// ---------- kernel 2: fused projections (5 jobs) ----------
// jobs: 0 = Q(x_a, wq)*CSCALE -> [BH,2048,32]
//       1 = K(x_a, wk_a) -> [BH,4096,32] rows 0..2047 (rho-permuted per 64)
//       2 = V(x_a, wv_a) -> [BH,64 tiles,8 units,32 d,8 keys] cols 0..2047
//       3 = K(x_b, wk_b) rows 2048..4095
//       4 = V(x_b, wv_b) cols 2048..4095
__global__ __launch_bounds__(256) void proj_kernel(
    const u16* __restrict__ xa_bf, const u16* __restrict__ xb_bf,
    const u16* __restrict__ wbase,
    const float* __restrict__ b0, const float* __restrict__ b1,
    const float* __restrict__ b2, const float* __restrict__ b3,
    const float* __restrict__ b4,
    u16* __restrict__ Qo, u16* __restrict__ Ko, u16* __restrict__ Vo) {
  int job = blockIdx.z;
  const u16* A = (job <= 2) ? xa_bf : xb_bf;
  const u16* W = wbase + job * 65536;
  const float* bias = job == 0 ? b0 : job == 1 ? b1 : job == 2 ? b2 : job == 3 ? b3 : b4;
  int mode = (job == 0) ? 0 : (job == 1 || job == 3) ? 1 : 2;
  int soff = (job >= 3) ? 2048 : 0;

  int tid = threadIdx.x, wid = tid >> 6, lane = tid & 63, g = lane >> 4, c = lane & 15;
  int m0 = blockIdx.x * 64, n0 = blockIdx.y * 64;
  const u16* Ap = A + (m0 + wid * 16 + c) * 256 + g * 8;
  const u16* Wp = W + (n0 + c) * 256 + g * 8;
  f32x4 acc[4] = {};
#pragma unroll
  for (int kk = 0; kk < 256; kk += 32) {
    bf16x8 af = *(const bf16x8*)(Ap + kk);
#pragma unroll
    for (int nt = 0; nt < 4; ++nt) {
      bf16x8 bfr = *(const bf16x8*)(Wp + nt * 4096 + kk);
      acc[nt] = mfma16(af, bfr, acc[nt]);
    }
  }
#pragma unroll
  for (int nt = 0; nt < 4; ++nt) {
    int f = n0 + nt * 16 + c;
    float bv = bias[f];
    int h = f >> 5, d = f & 31;
#pragma unroll
    for (int r = 0; r < 4; ++r) {
      int m = m0 + wid * 16 + g * 4 + r;
      int bq = m >> 11, n = m & 2047;
      int bh = bq * 8 + h;
      float y = acc[nt][r] + bv;
      if (mode == 0) {
        Qo[(bh * 2048 + n) * 32 + d] = f2bf(y * CSCALE);
      } else if (mode == 1) {
        int nk = soff + n;
        int pr = (nk & ~63) | rho(nk & 63);
        Ko[((size_t)bh * 4096 + pr) * 32 + d] = f2bf(y);
      } else {
        int nk = soff + n;
        // V layout: [bh][tile=nk>>6][unit=(nk>>3)&7][d][nk&7], u16 units
        Vo[(size_t)bh * 131072 + (nk >> 6) * 2048 + ((nk >> 3) & 7) * 256 +
           d * 8 + (nk & 7)] = f2bf(y);
      }
    }
  }
}

// ---------- kernel 3: flash attention, swapped-QK register softmax ----------
// grid 1024: xcd=bid&7, slot=bid>>3; bh=(xcd<<1)|(slot&1); rem=slot>>1:
// ks=rem&1 (key half), qi=rem>>1. 4 waves x 16 q-rows.
// Triple-buffered K/V (3 x (4KB K + 4KB V) = 24KB LDS), counted vmcnt,
// P stays in registers (K rows rho-permuted so PV a-frags are direct).
__global__ __launch_bounds__(256) void attn_kernel(
    const u16* __restrict__ Q, const u16* __restrict__ K,
    const u16* __restrict__ Vt, float* __restrict__ Zp, float* __restrict__ S) {
  __shared__ __align__(16) unsigned char sbuf[24576];
  // [0,12288): K triple buffer (3 x 64rows x 64B, xor-swizzled)
  // [12288,24576): V triple buffer (3 x [8 units][32 d] x 16B, linear)
  int bid = blockIdx.x;
  int xcd = bid & 7, slot = bid >> 3;
  int bh = (xcd << 1) | (slot & 1);
  int rem = slot >> 1;
  int ks = rem & 1, qi = rem >> 1;
  int tid = threadIdx.x, wid = tid >> 6, lane = tid & 63;
  int g = lane >> 4, c = lane & 15;
  int qbase = qi * 64 + wid * 16;

  const unsigned char* Kb =
      (const unsigned char*)K + ((size_t)bh * 4096 + ks * 2048) * 64;
  const unsigned char* Vb =
      (const unsigned char*)Vt + (size_t)bh * 262144 + (size_t)ks * 131072;

  bf16x8 qf = *(const bf16x8*)(Q + ((size_t)bh * 2048 + qbase + c) * 32 + g * 8);

  // lane-constant LDS read addresses
  int kaddr = c * 64 + ((g ^ ((c >> 1) & 3)) << 4);   // + s*1024
  int vaddr = g * 512 + c * 16;                        // z0/A0; +2048 A1; +256 z1

  // staging: linear LDS dest; K src inverse-swizzled, V src linear
  int o = wid * 1024 + (lane << 4);
  int ko_src = o ^ (((o >> 7) & 3) << 4);

  f32x4 z0 = {}, z1 = {};
  float lsum = 0.f;

  // prologue: stage tile 0 into buffer 0
  load_lds16(Kb + ko_src, sbuf + wid * 1024);
  load_lds16(Vb + o, sbuf + 12288 + wid * 1024);

  int cur = 0;
  for (int t = 0; t < 32; ++t) {
    int nxt = cur + 1;
    if (nxt == 3) nxt = 0;
    if (t + 1 < 32) {  // prefetch tile t+1 into buffer nxt
      load_lds16(Kb + (t + 1) * 4096 + ko_src, sbuf + nxt * 4096 + wid * 1024);
      load_lds16(Vb + (t + 1) * 4096 + o, sbuf + 12288 + nxt * 4096 + wid * 1024);
      __builtin_amdgcn_sched_barrier(0);
      asm volatile("s_waitcnt vmcnt(2)" ::: "memory");  // tile t (mine) done
    } else {
      __builtin_amdgcn_sched_barrier(0);
      asm volatile("s_waitcnt vmcnt(0)" ::: "memory");
    }
    __builtin_amdgcn_s_barrier();   // all waves' tile-t loads done
    __builtin_amdgcn_sched_barrier(0);

    const unsigned char* kbuf = sbuf + cur * 4096;
    const unsigned char* vbuf = sbuf + 12288 + cur * 4096;

    bf16x8 kf0 = *(const bf16x8*)(kbuf + kaddr);
    bf16x8 kf1 = *(const bf16x8*)(kbuf + kaddr + 1024);
    bf16x8 kf2 = *(const bf16x8*)(kbuf + kaddr + 2048);
    bf16x8 kf3 = *(const bf16x8*)(kbuf + kaddr + 3072);
    bf16x8 vf00 = *(const bf16x8*)(vbuf + vaddr);
    bf16x8 vf01 = *(const bf16x8*)(vbuf + vaddr + 2048);
    bf16x8 vf10 = *(const bf16x8*)(vbuf + vaddr + 256);
    bf16x8 vf11 = *(const bf16x8*)(vbuf + vaddr + 2048 + 256);

    f32x4 zz = {};
    __builtin_amdgcn_s_setprio(1);
    // swapped: st_s[r] = S^T[permuted keyrow s*16+g*4+r][q=c]
    f32x4 s0 = mfma16(kf0, qf, zz);
    f32x4 s1 = mfma16(kf1, qf, zz);
    f32x4 s2 = mfma16(kf2, qf, zz);
    f32x4 s3 = mfma16(kf3, qf, zz);
    __builtin_amdgcn_s_setprio(0);

    float e0[4], e1[4], e2[4], e3[4];
#pragma unroll
    for (int r = 0; r < 4; ++r) {
      e0[r] = __builtin_amdgcn_exp2f(s0[r]);
      e1[r] = __builtin_amdgcn_exp2f(s1[r]);
      e2[r] = __builtin_amdgcn_exp2f(s2[r]);
      e3[r] = __builtin_amdgcn_exp2f(s3[r]);
    }
    lsum += ((e0[0] + e0[1]) + (e0[2] + e0[3])) + ((e1[0] + e1[1]) + (e1[2] + e1[3])) +
            ((e2[0] + e2[1]) + (e2[2] + e2[3])) + ((e3[0] + e3[1]) + (e3[2] + e3[3]));

    // P fragments directly in registers: lane (g,c) holds q=c, keys 8g..8g+7
    // (rho made subtile s rows == the needed a-frag slots, zero cross-lane)
    union { u32 u[4]; bf16x8 v; } A0, A1;
    A0.u[0] = cvt_pk_bf16(e0[0], e0[1]);
    A0.u[1] = cvt_pk_bf16(e0[2], e0[3]);
    A0.u[2] = cvt_pk_bf16(e1[0], e1[1]);
    A0.u[3] = cvt_pk_bf16(e1[2], e1[3]);
    A1.u[0] = cvt_pk_bf16(e2[0], e2[1]);
    A1.u[1] = cvt_pk_bf16(e2[2], e2[3]);
    A1.u[2] = cvt_pk_bf16(e3[0], e3[1]);
    A1.u[3] = cvt_pk_bf16(e3[2], e3[3]);

    __builtin_amdgcn_s_setprio(1);
    z0 = mfma16(A0.v, vf00, z0);
    z0 = mfma16(A1.v, vf01, z0);
    z1 = mfma16(A0.v, vf10, z1);
    z1 = mfma16(A1.v, vf11, z1);
    __builtin_amdgcn_s_setprio(0);
    cur = nxt;
  }

  // row-sum: lanes (g,c) all hold partials for q=c; reduce over g
  lsum += __shfl_xor(lsum, 16);
  lsum += __shfl_xor(lsum, 32);

  size_t zrow = ((size_t)ks * 16 + bh) * 2048;
  if (lane < 16) S[zrow + qbase + lane] = lsum;
#pragma unroll
  for (int r = 0; r < 4; ++r) {
    int m = qbase + g * 4 + r;
    float* zp = Zp + (zrow + m) * 32;
    zp[c] = z0[r];
    zp[16 + c] = z1[r];
  }
}

// ---------- kernel 4: combine + out = Z @ w^T + b + x_a (fp32) ----------
// grid 256: block = 16 m-rows x full N=256; 4 waves, wid = n-quarter.
__global__ __launch_bounds__(256) void out_kernel(
    const float* __restrict__ Zp, const float* __restrict__ S,
    const u16* __restrict__ W, const float* __restrict__ bias,
    const float* __restrict__ resid, float* __restrict__ out) {
  int tid = threadIdx.x, wid = tid >> 6, lane = tid & 63, g = lane >> 4, c = lane & 15;
  int m0 = blockIdx.x * 16;
  int mrow = m0 + c;
  int bq = mrow >> 11, n = mrow & 2047;
  const u16* Wp = W + (wid * 64 + c) * 256 + g * 8;
  f32x4 acc[4] = {};
#pragma unroll
  for (int h = 0; h < 8; ++h) {
    int bh = bq * 8 + h;
    const float* za = Zp + ((size_t)bh * 2048 + n) * 32 + g * 8;
    const float* zb = za + (size_t)16 * 2048 * 32;
    float4 a0 = *(const float4*)za;
    float4 a1 = *(const float4*)(za + 4);
    float4 b0 = *(const float4*)zb;
    float4 b1 = *(const float4*)(zb + 4);
    float inv = 1.0f / (S[(size_t)bh * 2048 + n] + S[(size_t)(16 + bh) * 2048 + n]);
    union { u32 u[4]; bf16x8 v; } cv;
    cv.u[0] = pack_bf2((a0.x + b0.x) * inv, (a0.y + b0.y) * inv);
    cv.u[1] = pack_bf2((a0.z + b0.z) * inv, (a0.w + b0.w) * inv);
    cv.u[2] = pack_bf2((a1.x + b1.x) * inv, (a1.y + b1.y) * inv);
    cv.u[3] = pack_bf2((a1.z + b1.z) * inv, (a1.w + b1.w) * inv);
    bf16x8 af = cv.v;
#pragma unroll
    for (int nt = 0; nt < 4; ++nt) {
      bf16x8 bfr = *(const bf16x8*)(Wp + nt * 4096 + h * 32);
      acc[nt] = mfma16(af, bfr, acc[nt]);
    }
  }
#pragma unroll
  for (int nt = 0; nt < 4; ++nt) {
    int f = wid * 64 + nt * 16 + c;
    float bv = bias[f];
#pragma unroll
    for (int r = 0; r < 4; ++r) {
      int m = m0 + g * 4 + r;
      out[(size_t)m * 256 + f] = acc[nt][r] + bv + resid[(size_t)m * 256 + f];
    }
  }
}

// ---------- launch ----------
extern "C" void kernel_launch(void* const* d_in, const int* in_sizes, int n_in,
                              void* d_out, int out_size, void* d_ws, size_t ws_size,
                              hipStream_t stream) {
  const float* xa = (const float*)d_in[0];
  const float* xb = (const float*)d_in[1];
  const float* wq_w = (const float*)d_in[2];
  const float* wq_b = (const float*)d_in[3];
  const float* wka_w = (const float*)d_in[4];
  const float* wka_b = (const float*)d_in[5];
  const float* wkb_w = (const float*)d_in[6];
  const float* wkb_b = (const float*)d_in[7];
  const float* wva_w = (const float*)d_in[8];
  const float* wva_b = (const float*)d_in[9];
  const float* wvb_w = (const float*)d_in[10];
  const float* wvb_b = (const float*)d_in[11];
  const float* w_w = (const float*)d_in[12];
  const float* w_b = (const float*)d_in[13];

  u16* ws = (u16*)d_ws;
  u16* xa_bf = ws;                  // 1048576
  u16* xb_bf = ws + 1048576;        // 1048576
  u16* wbf = ws + 2097152;          // 6 * 65536
  u16* Qb = ws + 2490368;           // 1048576
  u16* Kb = ws + 3538944;           // 2097152
  u16* Vtb = ws + 5636096;          // 2097152
  float* Zp = (float*)(ws + 7733248);          // 2*16*2048*32 fp32 = 8 MB
  float* S = (float*)((char*)d_ws + 23855104); // 2*16*2048 fp32 = 256 KB
  // total ws: ~24.1 MB

  convert_kernel<<<1216, 256, 0, stream>>>(xa, xb, wq_w, wka_w, wva_w, wkb_w,
                                           wvb_w, w_w, ws);
  proj_kernel<<<dim3(64, 4, 5), 256, 0, stream>>>(
      xa_bf, xb_bf, wbf, wq_b, wka_b, wva_b, wkb_b, wvb_b, Qb, Kb, Vtb);
  attn_kernel<<<1024, 256, 0, stream>>>(Qb, Kb, Vtb, Zp, S);
  out_kernel<<<256, 256, 0, stream>>>(Zp, S, wbf + 5 * 65536, w_b, xa,
                                      (float*)d_out);
}